// Round 2
// baseline (10906.184 us; speedup 1.0000x reference)
//
#include <hip/hip_runtime.h>
#include <stdint.h>

// Problem constants
constexpr int T_STEPS = 512;
constexpr int BSZ     = 256;
constexpr int OBSD    = 64;
constexpr int HID     = 512;
constexpr int NROWS   = T_STEPS * BSZ;   // 131072

// LSTM partitioning: 8 groups x 32 WGs; group owns 32 batch rows; WG owns 16 h-cols
constexpr int GROUPS = 8;
constexpr int WPG    = 32;
constexpr int BW     = 32;

typedef __attribute__((ext_vector_type(8))) short bf16x8;
typedef __attribute__((ext_vector_type(4))) float f32x4;

__device__ __forceinline__ float bf2f(uint16_t u) {
  union { uint32_t i; float f; } v; v.i = ((uint32_t)u) << 16; return v.f;
}
__device__ __forceinline__ uint16_t f2bf(float f) {
  union { float f; uint32_t i; } v; v.f = f;
  return (uint16_t)((v.i + 0x7FFFu + ((v.i >> 16) & 1u)) >> 16);
}
__device__ __forceinline__ float sigm(float x) { return 1.f / (1.f + __expf(-x)); }
__device__ __forceinline__ float tanh_fast(float x) {
  float e = __expf(2.f * x);
  return 1.f - 2.f / (e + 1.f);
}

__device__ __forceinline__ void gll16(const void* g, void* l) {
  __builtin_amdgcn_global_load_lds(
      (const __attribute__((address_space(1))) uint32_t*)g,
      (__attribute__((address_space(3))) uint32_t*)l, 16, 0, 0);
}

// ---------------------------------------------------------------------------
// Persistent LSTM scan kernel. 256 blocks x 256 threads, 1 block/CU.
// LDS: Wf [4 gates][18 ksteps][64 lanes][8 bf16] = 73728 B  (MFMA B-frag layout)
//      Ab [32 rows][576 k] bf16, XOR-swizzled      = 36864 B
//      gl [4][32][16] f32 gate exchange            =  8192 B
//      bl [4][16] f32 bias                          =   256 B   total 119040 B
// Groups of 32 WGs are mutually independent -> no deadlock under partial
// residency (earlier groups drain, later blocks schedule).
// ---------------------------------------------------------------------------
__global__ __launch_bounds__(256, 1) void lstm_kernel(
    const float* __restrict__ xin, const float* __restrict__ done,
    const float* __restrict__ h0, const float* __restrict__ c0,
    const float* __restrict__ W_ih, const float* __restrict__ W_hh,
    const float* __restrict__ b_ih, const float* __restrict__ b_hh,
    uint16_t* __restrict__ hs, uint32_t* __restrict__ cnt,
    float* __restrict__ out)
{
  extern __shared__ char lds[];
  uint16_t* Wf = (uint16_t*)lds;
  char*     Ab = lds + 73728;
  float*    gl = (float*)(lds + 73728 + 36864);
  float*    bl = (float*)(lds + 73728 + 36864 + 8192);

  const int wg   = blockIdx.x;
  const int g    = wg / WPG;
  const int win  = wg % WPG;
  const int bg   = g * BW;
  const int tid  = threadIdx.x;
  const int lane = tid & 63;
  const int q    = tid >> 6;   // wave id == gate id (i,f,g,o)

  // ---- one-time: scatter this WG's weight rows into MFMA B-frag layout ----
  for (int i = 0; i < 18; ++i) {
    int slot = tid + i * 256;             // [0, 4608)
    int q2  = slot / (18 * 64);
    int rem = slot % (18 * 64);
    int ks  = rem >> 6;
    int l2  = rem & 63;
    int nl  = l2 & 15, kg = l2 >> 4;
    int grow = q2 * 512 + win * 16 + nl;  // global gate row
    const float* src = (ks < 16)
        ? (W_hh + (size_t)grow * 512 + ks * 32 + kg * 8)
        : (W_ih + (size_t)grow * 64 + (ks - 16) * 32 + kg * 8);
    uint4 u4;
    u4.x = (uint32_t)f2bf(src[0]) | ((uint32_t)f2bf(src[1]) << 16);
    u4.y = (uint32_t)f2bf(src[2]) | ((uint32_t)f2bf(src[3]) << 16);
    u4.z = (uint32_t)f2bf(src[4]) | ((uint32_t)f2bf(src[5]) << 16);
    u4.w = (uint32_t)f2bf(src[6]) | ((uint32_t)f2bf(src[7]) << 16);
    *(uint4*)(Wf + (size_t)slot * 8) = u4;
  }
  if (tid < 64) {
    int q2 = tid >> 4, c = tid & 15;
    int grow = q2 * 512 + win * 16 + c;
    bl[tid] = b_ih[grow] + b_hh[grow];
  }

  const int b_loc = tid >> 3;        // 0..31 (batch row within group)
  const int n0    = (tid & 7) * 2;   // h-col pair within WG's 16 cols
  float creg0 = c0[(size_t)(bg + b_loc) * HID + win * 16 + n0];
  float creg1 = c0[(size_t)(bg + b_loc) * HID + win * 16 + n0 + 1];

  const int sr  = tid >> 3;          // staging row
  const int sc8 = (tid & 7) * 8;     // x col base

  __syncthreads();

  for (int t = 0; t < T_STEPS; ++t) {
    // ---- stage x_t (independent of h, overlaps the wait) ----
    {
      const float* xp = xin + ((size_t)t * BSZ + bg + sr) * OBSD + sc8;
      float4 xa = *(const float4*)xp;
      float4 xb = *(const float4*)(xp + 4);
      uint4 u4;
      u4.x = (uint32_t)f2bf(xa.x) | ((uint32_t)f2bf(xa.y) << 16);
      u4.y = (uint32_t)f2bf(xa.z) | ((uint32_t)f2bf(xa.w) << 16);
      u4.z = (uint32_t)f2bf(xb.x) | ((uint32_t)f2bf(xb.y) << 16);
      u4.w = (uint32_t)f2bf(xb.z) | ((uint32_t)f2bf(xb.w) << 16);
      *(uint4*)(Ab + ((sr * 1152 + 1024 + sc8 * 2) ^ ((sr & 7) << 4))) = u4;
    }
    // ---- wait for the whole group's h_{t-1} ----
    if (t > 0 && tid == 0) {
      while (__hip_atomic_load(cnt + (size_t)(t - 1) * GROUPS + g,
                               __ATOMIC_ACQUIRE, __HIP_MEMORY_SCOPE_AGENT) < (uint32_t)WPG)
        __builtin_amdgcn_s_sleep(1);
    }
    __syncthreads();
    // ---- stage h_{t-1} with done-mask into Ab ----
    {
      float dv = done[(size_t)t * BSZ + bg + sr];
      bool rst = dv > 0.5f;
      if (t == 0) {
        const float* hp = h0 + (size_t)(bg + sr) * HID;
        #pragma unroll 4
        for (int j = 0; j < 16; ++j) {
          int u = (tid & 7) * 16 + j;
          float4 hv = *(const float4*)(hp + u * 4);
          uint64_t v = 0;
          if (!rst) {
            uint32_t lo = (uint32_t)f2bf(hv.x) | ((uint32_t)f2bf(hv.y) << 16);
            uint32_t hi = (uint32_t)f2bf(hv.z) | ((uint32_t)f2bf(hv.w) << 16);
            v = (uint64_t)lo | ((uint64_t)hi << 32);
          }
          *(uint64_t*)(Ab + ((sr * 1152 + u * 8) ^ ((sr & 7) << 4))) = v;
        }
      } else {
        const uint64_t* hrow = (const uint64_t*)hs + ((size_t)(t - 1) * BSZ + bg + sr) * 128;
        #pragma unroll 4
        for (int j = 0; j < 16; ++j) {
          int u = (tid & 7) * 16 + j;
          uint64_t v = __hip_atomic_load(hrow + u, __ATOMIC_RELAXED, __HIP_MEMORY_SCOPE_AGENT);
          if (rst) v = 0;
          *(uint64_t*)(Ab + ((sr * 1152 + u * 8) ^ ((sr & 7) << 4))) = v;
        }
      }
    }
    __syncthreads();
    // ---- MFMA: gates[32 batch, 16 cols] for wave's gate q ----
    f32x4 ac0 = {0.f, 0.f, 0.f, 0.f};
    f32x4 ac1 = {0.f, 0.f, 0.f, 0.f};
    {
      const int ar = lane & 15;
      const int kg = lane >> 4;
      #pragma unroll
      for (int ks = 0; ks < 18; ++ks) {
        int kb = (ks * 32 + kg * 8) * 2;
        bf16x8 a0 = *(const bf16x8*)(Ab + ((ar * 1152 + kb) ^ ((ar & 7) << 4)));
        bf16x8 a1 = *(const bf16x8*)(Ab + (((ar + 16) * 1152 + kb) ^ ((ar & 7) << 4)));
        bf16x8 bq = *(const bf16x8*)(Wf + (size_t)((q * 18 + ks) * 64 + lane) * 8);
        ac0 = __builtin_amdgcn_mfma_f32_16x16x32_bf16(a0, bq, ac0, 0, 0, 0);
        ac1 = __builtin_amdgcn_mfma_f32_16x16x32_bf16(a1, bq, ac1, 0, 0, 0);
      }
    }
    // ---- gates -> LDS exchange ----
    {
      int c  = lane & 15;
      int rb = (lane >> 4) * 4;
      #pragma unroll
      for (int r = 0; r < 4; ++r) {
        gl[q * 512 + (rb + r) * 16 + c]      = ac0[r];
        gl[q * 512 + (16 + rb + r) * 16 + c] = ac1[r];
      }
    }
    __syncthreads();
    // ---- cell update (c lives in registers across all 512 steps) ----
    {
      float dv = done[(size_t)t * BSZ + bg + b_loc];
      float m = dv > 0.5f ? 0.f : 1.f;
      float h0v, h1v;
      {
        float I = gl[b_loc * 16 + n0]          + bl[n0];
        float F = gl[512 + b_loc * 16 + n0]    + bl[16 + n0];
        float G = gl[1024 + b_loc * 16 + n0]   + bl[32 + n0];
        float O = gl[1536 + b_loc * 16 + n0]   + bl[48 + n0];
        float cc = creg0 * m;
        cc = sigm(F) * cc + sigm(I) * tanh_fast(G);
        creg0 = cc;
        h0v = sigm(O) * tanh_fast(cc);
      }
      {
        int n1 = n0 + 1;
        float I = gl[b_loc * 16 + n1]          + bl[n1];
        float F = gl[512 + b_loc * 16 + n1]    + bl[16 + n1];
        float G = gl[1024 + b_loc * 16 + n1]   + bl[32 + n1];
        float O = gl[1536 + b_loc * 16 + n1]   + bl[48 + n1];
        float cc = creg1 * m;
        cc = sigm(F) * cc + sigm(I) * tanh_fast(G);
        creg1 = cc;
        h1v = sigm(O) * tanh_fast(cc);
      }
      uint32_t pk = (uint32_t)f2bf(h0v) | ((uint32_t)f2bf(h1v) << 16);
      uint32_t* hp = (uint32_t*)(hs + ((size_t)t * BSZ + bg + b_loc) * HID + win * 16 + n0);
      __hip_atomic_store(hp, pk, __ATOMIC_RELAXED, __HIP_MEMORY_SCOPE_AGENT);
      if (t == T_STEPS - 1) {
        size_t ob = (size_t)(bg + b_loc) * HID + win * 16 + n0;
        out[NROWS + ob]         = h0v;
        out[NROWS + ob + 1]     = h1v;
        out[2 * NROWS + ob]     = creg0;
        out[2 * NROWS + ob + 1] = creg1;
      }
    }
    __syncthreads();   // all h stores drained (vmcnt 0) before arrival
    if (tid == 0)
      __hip_atomic_fetch_add(cnt + (size_t)t * GROUPS + g, 1u,
                             __ATOMIC_RELEASE, __HIP_MEMORY_SCOPE_AGENT);
  }
}

// ---------------------------------------------------------------------------
// Per-row LayerNorm stats from bf16 hidden: rstd[m], murs[m] = mu*rstd.
// One wave per row.
// ---------------------------------------------------------------------------
__global__ void ln_stats_kernel(const uint16_t* __restrict__ hsrc,
                                float* __restrict__ rstd_a, float* __restrict__ murs_a)
{
  const int lane = threadIdx.x & 63;
  const size_t row = (size_t)blockIdx.x * 4 + (threadIdx.x >> 6);
  bf16x8 v = *(const bf16x8*)(hsrc + row * 512 + lane * 8);
  float s = 0.f, s2 = 0.f;
  #pragma unroll
  for (int j = 0; j < 8; ++j) { float f = bf2f((uint16_t)v[j]); s += f; s2 += f * f; }
  #pragma unroll
  for (int o = 1; o < 64; o <<= 1) { s += __shfl_xor(s, o); s2 += __shfl_xor(s2, o); }
  if (lane == 0) {
    float mu  = s * (1.f / 512.f);
    float var = s2 * (1.f / 512.f) - mu * mu;
    float rs  = rsqrtf(var + 1e-5f);
    rstd_a[row] = rs;
    murs_a[row] = mu * rs;
  }
}

// ---------------------------------------------------------------------------
// u[n] = sum_k ln_b[k]*W1[n,k] + b1[n] ;  v[n] = sum_k ln_g[k]*W1[n,k]
// One wave per n-row (512 rows).
// ---------------------------------------------------------------------------
__global__ void uv_kernel(const float* __restrict__ W1, const float* __restrict__ ln_g,
                          const float* __restrict__ ln_b, const float* __restrict__ b1,
                          float* __restrict__ u, float* __restrict__ v)
{
  const int lane = threadIdx.x & 63;
  const int row  = blockIdx.x * 4 + (threadIdx.x >> 6);
  const float* wp = W1 + (size_t)row * 512 + lane * 8;
  float4 w0 = *(const float4*)wp;
  float4 w1 = *(const float4*)(wp + 4);
  float4 g0 = *(const float4*)(ln_g + lane * 8);
  float4 g1 = *(const float4*)(ln_g + lane * 8 + 4);
  float4 b0 = *(const float4*)(ln_b + lane * 8);
  float4 b1v = *(const float4*)(ln_b + lane * 8 + 4);
  float su = b0.x * w0.x + b0.y * w0.y + b0.z * w0.z + b0.w * w0.w
           + b1v.x * w1.x + b1v.y * w1.y + b1v.z * w1.z + b1v.w * w1.w;
  float sv = g0.x * w0.x + g0.y * w0.y + g0.z * w0.z + g0.w * w0.w
           + g1.x * w1.x + g1.y * w1.y + g1.z * w1.z + g1.w * w1.w;
  #pragma unroll
  for (int o = 1; o < 64; o <<= 1) { su += __shfl_xor(su, o); sv += __shfl_xor(sv, o); }
  if (lane == 0) { u[row] = su + b1[row]; v[row] = sv; }
}

// ---------------------------------------------------------------------------
// Fused GEMM: C = tanh(epilogue(A[64 rows, K=512] @ W[,512]^T))
// A staged full-K in LDS once (64KB, swizzled) -> in-place C writes are safe.
// MODE 0: LN-affine epilogue  tanh(rstd_m*G - murs_m*v_n + u_n)   (u has +b1)
// MODE 1: bias epilogue       tanh(G + bias_n)
// grid: M/64 blocks x 256 thr (4 waves: 2n x 2m over [64m x 128n] per n-tile).
// ---------------------------------------------------------------------------
template<int MODE>
__global__ __launch_bounds__(256, 2) void gemm_fused(
    const uint16_t* __restrict__ Abase, const uint16_t* __restrict__ W,
    uint16_t* __restrict__ C, int ntiles,
    const float* __restrict__ rstd_a, const float* __restrict__ murs_a,
    const float* __restrict__ uvec, const float* __restrict__ vvec,
    const float* __restrict__ bias)
{
  __shared__ uint16_t At[64 * 512];   // 65536 B
  const int tid  = threadIdx.x;
  const int lane = tid & 63;
  const int wv   = tid >> 6;
  const size_t mbase = (size_t)blockIdx.x * 64;

  // stage 64 rows x full K, pre-swizzled source -> linear LDS dest
  for (int r8 = 0; r8 < 16; ++r8) {
    int row = wv * 16 + r8;
    int sb  = (lane * 16) ^ ((row & 7) << 4);       // byte pos in 1024B row
    gll16(Abase + (mbase + row) * 512 + sb / 2, At + row * 512);
  }
  __syncthreads();

  const int fr = lane & 15, kg = lane >> 4;
  const int mloc = (wv & 1) * 32;
  const int nhalf = (wv >> 1) * 64;

  for (int nt = 0; nt < ntiles; ++nt) {
    const int nbase = nt * 128 + nhalf;
    f32x4 vz = {0.f, 0.f, 0.f, 0.f};
    f32x4 acc[4][2];
    #pragma unroll
    for (int i = 0; i < 4; ++i) { acc[i][0] = vz; acc[i][1] = vz; }

    #pragma unroll 4
    for (int kb = 0; kb < 16; ++kb) {
      const int ke = kb * 32 + kg * 8;              // element offset in K
      bf16x8 wf[4];
      #pragma unroll
      for (int i = 0; i < 4; ++i)
        wf[i] = *(const bf16x8*)(W + (size_t)(nbase + i * 16 + fr) * 512 + ke);
      bf16x8 af[2];
      #pragma unroll
      for (int j = 0; j < 2; ++j) {
        int mr = mloc + j * 16 + fr;
        af[j] = *(const bf16x8*)((const char*)At + ((mr * 1024 + ke * 2) ^ ((mr & 7) << 4)));
      }
      #pragma unroll
      for (int i = 0; i < 4; ++i)
        #pragma unroll
        for (int j = 0; j < 2; ++j)
          acc[i][j] = __builtin_amdgcn_mfma_f32_16x16x32_bf16(wf[i], af[j], acc[i][j], 0, 0, 0);
    }

    #pragma unroll
    for (int j = 0; j < 2; ++j) {
      size_t m = mbase + mloc + j * 16 + fr;
      float rs = 0.f, mrs = 0.f;
      if constexpr (MODE == 0) { rs = rstd_a[m]; mrs = murs_a[m]; }
      #pragma unroll
      for (int i = 0; i < 4; ++i) {
        int n = nbase + i * 16 + kg * 4;
        float o0, o1, o2, o3;
        if constexpr (MODE == 0) {
          float4 uu = *(const float4*)(uvec + n);
          float4 vv = *(const float4*)(vvec + n);
          o0 = tanh_fast(rs * acc[i][j][0] - mrs * vv.x + uu.x);
          o1 = tanh_fast(rs * acc[i][j][1] - mrs * vv.y + uu.y);
          o2 = tanh_fast(rs * acc[i][j][2] - mrs * vv.z + uu.z);
          o3 = tanh_fast(rs * acc[i][j][3] - mrs * vv.w + uu.w);
        } else {
          float4 bb = *(const float4*)(bias + n);
          o0 = tanh_fast(acc[i][j][0] + bb.x);
          o1 = tanh_fast(acc[i][j][1] + bb.y);
          o2 = tanh_fast(acc[i][j][2] + bb.z);
          o3 = tanh_fast(acc[i][j][3] + bb.w);
        }
        uint32_t lo = (uint32_t)f2bf(o0) | ((uint32_t)f2bf(o1) << 16);
        uint32_t hi = (uint32_t)f2bf(o2) | ((uint32_t)f2bf(o3) << 16);
        *(uint64_t*)(C + m * 512 + n) = (uint64_t)lo | ((uint64_t)hi << 32);
      }
    }
    __syncthreads();  // keep waves together before next n-tile reads At
  }
}

// ---------------------------------------------------------------------------
// value[m] = a2[m,:256] . Wv + bv   (a2 at stride 512; one wave per row)
// ---------------------------------------------------------------------------
__global__ void gemv_kernel(const uint16_t* __restrict__ a2, const float* __restrict__ Wv,
                            const float* __restrict__ bv, float* __restrict__ outv)
{
  const int lane = threadIdx.x & 63;
  const size_t row = (size_t)blockIdx.x * 4 + (threadIdx.x >> 6);
  const uint16_t* p = a2 + row * 512 + lane * 4;
  uint64_t v = *(const uint64_t*)p;
  float4 w = *(const float4*)(Wv + lane * 4);
  float d = bf2f((uint16_t)(v & 0xFFFF)) * w.x
          + bf2f((uint16_t)((v >> 16) & 0xFFFF)) * w.y
          + bf2f((uint16_t)((v >> 32) & 0xFFFF)) * w.z
          + bf2f((uint16_t)((v >> 48) & 0xFFFF)) * w.w;
  #pragma unroll
  for (int o = 1; o < 64; o <<= 1) d += __shfl_xor(d, o);
  if (lane == 0) outv[row] = d + bv[0];
}

// ---------------------------------------------------------------------------
// W1 (fold ln_g into columns) then W2, fp32 -> bf16 contiguous.
// ---------------------------------------------------------------------------
__global__ void wconv_kernel(const float* __restrict__ W1, const float* __restrict__ W2,
                             const float* __restrict__ ln_g, uint16_t* __restrict__ dst)
{
  int idx = blockIdx.x * 256 + threadIdx.x;
  int i4 = idx * 4;
  float4 v;
  if (i4 < 262144) {
    v = *(const float4*)(W1 + i4);
    int c = i4 & 511;
    float4 gv = *(const float4*)(ln_g + c);
    v.x *= gv.x; v.y *= gv.y; v.z *= gv.z; v.w *= gv.w;
  } else {
    v = *(const float4*)(W2 + (i4 - 262144));
  }
  uint32_t lo = (uint32_t)f2bf(v.x) | ((uint32_t)f2bf(v.y) << 16);
  uint32_t hi = (uint32_t)f2bf(v.z) | ((uint32_t)f2bf(v.w) << 16);
  *(uint64_t*)(dst + i4) = (uint64_t)lo | ((uint64_t)hi << 32);
}

extern "C" void kernel_launch(void* const* d_in, const int* in_sizes, int n_in,
                              void* d_out, int out_size, void* d_ws, size_t ws_size,
                              hipStream_t stream)
{
  (void)in_sizes; (void)n_in;
  const float* x    = (const float*)d_in[0];
  const float* done = (const float*)d_in[1];
  const float* h0   = (const float*)d_in[2];
  const float* c0   = (const float*)d_in[3];
  const float* W_ih = (const float*)d_in[4];
  const float* W_hh = (const float*)d_in[5];
  const float* b_ih = (const float*)d_in[6];
  const float* b_hh = (const float*)d_in[7];
  const float* ln_g = (const float*)d_in[8];
  const float* ln_b = (const float*)d_in[9];
  const float* W1   = (const float*)d_in[10];
  const float* b1   = (const float*)d_in[11];
  const float* W2   = (const float*)d_in[12];
  const float* b2   = (const float*)d_in[13];
  const float* Wv   = (const float*)d_in[14];
  const float* bv   = (const float*)d_in[15];
  float* out = (float*)d_out;
  char* ws = (char*)d_ws;

  // ws layout (bytes):
  //   0        cnt      16384
  //   16384    wbf      786432   (bf16 W1g | W2)
  //   802816   u,v      4096     (512 f32 each)
  //   806912   rstd     524288
  //   1331200  murs     524288
  //   2097152  hs       134217728  (bf16 [T*B,512]; later a1 in-place, a2 cols 0..255)
  constexpr size_t NEED = 2097152ULL + 134217728ULL;
  if (ws_size < NEED) {
    // diagnosable fallback instead of an OOB fault
    hipMemsetAsync(d_out, 0, (size_t)out_size * 4, stream);
    return;
  }
  uint32_t* cnt  = (uint32_t*)ws;
  uint16_t* wbf  = (uint16_t*)(ws + 16384);
  float*    uv_u = (float*)(ws + 802816);
  float*    uv_v = (float*)(ws + 802816 + 2048);
  float*    rstd = (float*)(ws + 806912);
  float*    murs = (float*)(ws + 1331200);
  uint16_t* hsb  = (uint16_t*)(ws + 2097152);

  hipMemsetAsync(cnt, 0, 16384, stream);
  hipLaunchKernelGGL(wconv_kernel, dim3(384), dim3(256), 0, stream, W1, W2, ln_g, wbf);
  hipLaunchKernelGGL(uv_kernel, dim3(128), dim3(256), 0, stream, W1, ln_g, ln_b, b1, uv_u, uv_v);
  hipFuncSetAttribute((const void*)lstm_kernel,
                      hipFuncAttributeMaxDynamicSharedMemorySize, 131072);
  hipLaunchKernelGGL(lstm_kernel, dim3(256), dim3(256), 119040, stream,
                     x, done, h0, c0, W_ih, W_hh, b_ih, b_hh, hsb, cnt, out);
  hipLaunchKernelGGL(ln_stats_kernel, dim3(32768), dim3(256), 0, stream, hsb, rstd, murs);
  // GEMM1: a1 = tanh(LN(h) @ W1^T + b1), in-place over hs
  hipLaunchKernelGGL((gemm_fused<0>), dim3(2048), dim3(256), 0, stream,
                     hsb, wbf, hsb, 4, rstd, murs, uv_u, uv_v, (const float*)nullptr);
  // GEMM2: a2 = tanh(a1 @ W2^T + b2), in-place over hs cols [0,256)
  hipLaunchKernelGGL((gemm_fused<1>), dim3(2048), dim3(256), 0, stream,
                     hsb, wbf + 262144, hsb, 2,
                     (const float*)nullptr, (const float*)nullptr,
                     (const float*)nullptr, (const float*)nullptr, b2);
  hipLaunchKernelGGL(gemv_kernel, dim3(32768), dim3(256), 0, stream, hsb, Wv, bv, out);
}

// Round 3
// 5968.116 us; speedup vs baseline: 1.8274x; 1.8274x over previous
//
#include <hip/hip_runtime.h>
#include <stdint.h>

// Problem constants
constexpr int T_STEPS = 512;
constexpr int BSZ     = 256;
constexpr int OBSD    = 64;
constexpr int HID     = 512;
constexpr int NROWS   = T_STEPS * BSZ;   // 131072

// LSTM partitioning: 8 groups x 32 WGs; group owns 32 batch rows; WG owns 16 h-cols
constexpr int GROUPS = 8;
constexpr int WPG    = 32;
constexpr int BW     = 32;

typedef __attribute__((ext_vector_type(8))) short bf16x8;
typedef __attribute__((ext_vector_type(4))) float f32x4;

__device__ __forceinline__ float bf2f(uint16_t u) {
  union { uint32_t i; float f; } v; v.i = ((uint32_t)u) << 16; return v.f;
}
__device__ __forceinline__ uint16_t f2bf(float f) {
  union { float f; uint32_t i; } v; v.f = f;
  return (uint16_t)((v.i + 0x7FFFu + ((v.i >> 16) & 1u)) >> 16);
}
__device__ __forceinline__ float sigm(float x) { return 1.f / (1.f + __expf(-x)); }
__device__ __forceinline__ float tanh_fast(float x) {
  float e = __expf(2.f * x);
  return 1.f - 2.f / (e + 1.f);
}

__device__ __forceinline__ void gll16(const void* g, void* l) {
  __builtin_amdgcn_global_load_lds(
      (const __attribute__((address_space(1))) uint32_t*)g,
      (__attribute__((address_space(3))) uint32_t*)l, 16, 0, 0);
}

// ---------------------------------------------------------------------------
// Persistent LSTM scan kernel. 256 blocks x 256 threads, 1 block/CU.
// Sync: versioned per-WG flags (no RMW). flag[g*32+win] = t+1 (RELEASE) after
// step t's h-stores drain; waiters poll RELAXED (lanes 0..31, one 128B
// coalesced read / poll) + single acquire fence. Group flag blocks are 128B
// apart -> no cross-group line sharing. Monotonic values -> no re-init races.
// LDS: Wf 73728 B | Ab 36864 B | gl 8192 B | bl 256 B  = 119040 B
// ---------------------------------------------------------------------------
__global__ __launch_bounds__(256, 1) void lstm_kernel(
    const float* __restrict__ xin, const float* __restrict__ done,
    const float* __restrict__ h0, const float* __restrict__ c0,
    const float* __restrict__ W_ih, const float* __restrict__ W_hh,
    const float* __restrict__ b_ih, const float* __restrict__ b_hh,
    uint16_t* __restrict__ hs, uint32_t* __restrict__ flg,
    float* __restrict__ out)
{
  extern __shared__ char lds[];
  uint16_t* Wf = (uint16_t*)lds;
  char*     Ab = lds + 73728;
  float*    gl = (float*)(lds + 73728 + 36864);
  float*    bl = (float*)(lds + 73728 + 36864 + 8192);

  const int wg   = blockIdx.x;
  const int g    = wg / WPG;
  const int win  = wg % WPG;
  const int bg   = g * BW;
  const int tid  = threadIdx.x;
  const int lane = tid & 63;
  const int q    = tid >> 6;   // wave id == gate id (i,f,g,o)

  // ---- one-time: scatter this WG's weight rows into MFMA B-frag layout ----
  for (int i = 0; i < 18; ++i) {
    int slot = tid + i * 256;             // [0, 4608)
    int q2  = slot / (18 * 64);
    int rem = slot % (18 * 64);
    int ks  = rem >> 6;
    int l2  = rem & 63;
    int nl  = l2 & 15, kg = l2 >> 4;
    int grow = q2 * 512 + win * 16 + nl;  // global gate row
    const float* src = (ks < 16)
        ? (W_hh + (size_t)grow * 512 + ks * 32 + kg * 8)
        : (W_ih + (size_t)grow * 64 + (ks - 16) * 32 + kg * 8);
    uint4 u4;
    u4.x = (uint32_t)f2bf(src[0]) | ((uint32_t)f2bf(src[1]) << 16);
    u4.y = (uint32_t)f2bf(src[2]) | ((uint32_t)f2bf(src[3]) << 16);
    u4.z = (uint32_t)f2bf(src[4]) | ((uint32_t)f2bf(src[5]) << 16);
    u4.w = (uint32_t)f2bf(src[6]) | ((uint32_t)f2bf(src[7]) << 16);
    *(uint4*)(Wf + (size_t)slot * 8) = u4;
  }
  if (tid < 64) {
    int q2 = tid >> 4, c = tid & 15;
    int grow = q2 * 512 + win * 16 + c;
    bl[tid] = b_ih[grow] + b_hh[grow];
  }

  const int b_loc = tid >> 3;        // 0..31 (batch row within group)
  const int n0    = (tid & 7) * 2;   // h-col pair within WG's 16 cols
  float creg0 = c0[(size_t)(bg + b_loc) * HID + win * 16 + n0];
  float creg1 = c0[(size_t)(bg + b_loc) * HID + win * 16 + n0 + 1];

  const int sr  = tid >> 3;          // staging row
  const int sc8 = (tid & 7) * 8;     // x col base

  __syncthreads();

  for (int t = 0; t < T_STEPS; ++t) {
    // ---- stage x_t (independent of h, overlaps the wait) ----
    {
      const float* xp = xin + ((size_t)t * BSZ + bg + sr) * OBSD + sc8;
      float4 xa = *(const float4*)xp;
      float4 xb = *(const float4*)(xp + 4);
      uint4 u4;
      u4.x = (uint32_t)f2bf(xa.x) | ((uint32_t)f2bf(xa.y) << 16);
      u4.y = (uint32_t)f2bf(xa.z) | ((uint32_t)f2bf(xa.w) << 16);
      u4.z = (uint32_t)f2bf(xb.x) | ((uint32_t)f2bf(xb.y) << 16);
      u4.w = (uint32_t)f2bf(xb.z) | ((uint32_t)f2bf(xb.w) << 16);
      *(uint4*)(Ab + ((sr * 1152 + 1024 + sc8 * 2) ^ ((sr & 7) << 4))) = u4;
    }
    // ---- wait for the whole group's step t-1 flags (wave 0 only) ----
    if (t > 0 && q == 0) {
      for (;;) {
        uint32_t f = (lane < WPG)
            ? __hip_atomic_load(flg + g * 32 + lane, __ATOMIC_RELAXED, __HIP_MEMORY_SCOPE_AGENT)
            : 0xFFFFFFFFu;
        if (__all((int)(f >= (uint32_t)t))) break;
        __builtin_amdgcn_s_sleep(2);
      }
      __builtin_amdgcn_fence(__ATOMIC_ACQUIRE, "agent");
    }
    __syncthreads();
    // ---- stage h_{t-1} with done-mask into Ab ----
    {
      float dv = done[(size_t)t * BSZ + bg + sr];
      bool rst = dv > 0.5f;
      if (t == 0) {
        const float* hp = h0 + (size_t)(bg + sr) * HID;
        #pragma unroll 4
        for (int j = 0; j < 16; ++j) {
          int u = (tid & 7) * 16 + j;
          float4 hv = *(const float4*)(hp + u * 4);
          uint64_t v = 0;
          if (!rst) {
            uint32_t lo = (uint32_t)f2bf(hv.x) | ((uint32_t)f2bf(hv.y) << 16);
            uint32_t hi = (uint32_t)f2bf(hv.z) | ((uint32_t)f2bf(hv.w) << 16);
            v = (uint64_t)lo | ((uint64_t)hi << 32);
          }
          *(uint64_t*)(Ab + ((sr * 1152 + u * 8) ^ ((sr & 7) << 4))) = v;
        }
      } else {
        const uint64_t* hrow = (const uint64_t*)hs + ((size_t)(t - 1) * BSZ + bg + sr) * 128;
        #pragma unroll 4
        for (int j = 0; j < 16; ++j) {
          int u = (tid & 7) * 16 + j;
          uint64_t v = __hip_atomic_load(hrow + u, __ATOMIC_RELAXED, __HIP_MEMORY_SCOPE_AGENT);
          if (rst) v = 0;
          *(uint64_t*)(Ab + ((sr * 1152 + u * 8) ^ ((sr & 7) << 4))) = v;
        }
      }
    }
    __syncthreads();
    // ---- MFMA: gates[32 batch, 16 cols] for wave's gate q ----
    f32x4 ac0 = {0.f, 0.f, 0.f, 0.f};
    f32x4 ac1 = {0.f, 0.f, 0.f, 0.f};
    {
      const int ar = lane & 15;
      const int kg = lane >> 4;
      #pragma unroll
      for (int ks = 0; ks < 18; ++ks) {
        int kb = (ks * 32 + kg * 8) * 2;
        bf16x8 a0 = *(const bf16x8*)(Ab + ((ar * 1152 + kb) ^ ((ar & 7) << 4)));
        bf16x8 a1 = *(const bf16x8*)(Ab + (((ar + 16) * 1152 + kb) ^ ((ar & 7) << 4)));
        bf16x8 bq = *(const bf16x8*)(Wf + (size_t)((q * 18 + ks) * 64 + lane) * 8);
        ac0 = __builtin_amdgcn_mfma_f32_16x16x32_bf16(a0, bq, ac0, 0, 0, 0);
        ac1 = __builtin_amdgcn_mfma_f32_16x16x32_bf16(a1, bq, ac1, 0, 0, 0);
      }
    }
    // ---- gates -> LDS exchange ----
    {
      int c  = lane & 15;
      int rb = (lane >> 4) * 4;
      #pragma unroll
      for (int r = 0; r < 4; ++r) {
        gl[q * 512 + (rb + r) * 16 + c]      = ac0[r];
        gl[q * 512 + (16 + rb + r) * 16 + c] = ac1[r];
      }
    }
    __syncthreads();
    // ---- cell update (c lives in registers across all 512 steps) ----
    {
      float dv = done[(size_t)t * BSZ + bg + b_loc];
      float m = dv > 0.5f ? 0.f : 1.f;
      float h0v, h1v;
      {
        float I = gl[b_loc * 16 + n0]          + bl[n0];
        float F = gl[512 + b_loc * 16 + n0]    + bl[16 + n0];
        float G = gl[1024 + b_loc * 16 + n0]   + bl[32 + n0];
        float O = gl[1536 + b_loc * 16 + n0]   + bl[48 + n0];
        float cc = creg0 * m;
        cc = sigm(F) * cc + sigm(I) * tanh_fast(G);
        creg0 = cc;
        h0v = sigm(O) * tanh_fast(cc);
      }
      {
        int n1 = n0 + 1;
        float I = gl[b_loc * 16 + n1]          + bl[n1];
        float F = gl[512 + b_loc * 16 + n1]    + bl[16 + n1];
        float G = gl[1024 + b_loc * 16 + n1]   + bl[32 + n1];
        float O = gl[1536 + b_loc * 16 + n1]   + bl[48 + n1];
        float cc = creg1 * m;
        cc = sigm(F) * cc + sigm(I) * tanh_fast(G);
        creg1 = cc;
        h1v = sigm(O) * tanh_fast(cc);
      }
      uint32_t pk = (uint32_t)f2bf(h0v) | ((uint32_t)f2bf(h1v) << 16);
      uint32_t* hp = (uint32_t*)(hs + ((size_t)t * BSZ + bg + b_loc) * HID + win * 16 + n0);
      __hip_atomic_store(hp, pk, __ATOMIC_RELAXED, __HIP_MEMORY_SCOPE_AGENT);
      if (t == T_STEPS - 1) {
        size_t ob = (size_t)(bg + b_loc) * HID + win * 16 + n0;
        out[NROWS + ob]         = h0v;
        out[NROWS + ob + 1]     = h1v;
        out[2 * NROWS + ob]     = creg0;
        out[2 * NROWS + ob + 1] = creg1;
      }
    }
    __syncthreads();   // per-wave vmcnt(0) drain before barrier -> h visible
    if (tid == 0)
      __hip_atomic_store(flg + g * 32 + win, (uint32_t)(t + 1),
                         __ATOMIC_RELEASE, __HIP_MEMORY_SCOPE_AGENT);
  }
}

// ---------------------------------------------------------------------------
// Per-row LayerNorm stats from bf16 hidden: rstd[m], murs[m] = mu*rstd.
// One wave per row.
// ---------------------------------------------------------------------------
__global__ void ln_stats_kernel(const uint16_t* __restrict__ hsrc,
                                float* __restrict__ rstd_a, float* __restrict__ murs_a)
{
  const int lane = threadIdx.x & 63;
  const size_t row = (size_t)blockIdx.x * 4 + (threadIdx.x >> 6);
  bf16x8 v = *(const bf16x8*)(hsrc + row * 512 + lane * 8);
  float s = 0.f, s2 = 0.f;
  #pragma unroll
  for (int j = 0; j < 8; ++j) { float f = bf2f((uint16_t)v[j]); s += f; s2 += f * f; }
  #pragma unroll
  for (int o = 1; o < 64; o <<= 1) { s += __shfl_xor(s, o); s2 += __shfl_xor(s2, o); }
  if (lane == 0) {
    float mu  = s * (1.f / 512.f);
    float var = s2 * (1.f / 512.f) - mu * mu;
    float rs  = rsqrtf(var + 1e-5f);
    rstd_a[row] = rs;
    murs_a[row] = mu * rs;
  }
}

// ---------------------------------------------------------------------------
// u[n] = sum_k ln_b[k]*W1[n,k] + b1[n] ;  v[n] = sum_k ln_g[k]*W1[n,k]
// One wave per n-row (512 rows).
// ---------------------------------------------------------------------------
__global__ void uv_kernel(const float* __restrict__ W1, const float* __restrict__ ln_g,
                          const float* __restrict__ ln_b, const float* __restrict__ b1,
                          float* __restrict__ u, float* __restrict__ v)
{
  const int lane = threadIdx.x & 63;
  const int row  = blockIdx.x * 4 + (threadIdx.x >> 6);
  const float* wp = W1 + (size_t)row * 512 + lane * 8;
  float4 w0 = *(const float4*)wp;
  float4 w1 = *(const float4*)(wp + 4);
  float4 g0 = *(const float4*)(ln_g + lane * 8);
  float4 g1 = *(const float4*)(ln_g + lane * 8 + 4);
  float4 b0 = *(const float4*)(ln_b + lane * 8);
  float4 b1v = *(const float4*)(ln_b + lane * 8 + 4);
  float su = b0.x * w0.x + b0.y * w0.y + b0.z * w0.z + b0.w * w0.w
           + b1v.x * w1.x + b1v.y * w1.y + b1v.z * w1.z + b1v.w * w1.w;
  float sv = g0.x * w0.x + g0.y * w0.y + g0.z * w0.z + g0.w * w0.w
           + g1.x * w1.x + g1.y * w1.y + g1.z * w1.z + g1.w * w1.w;
  #pragma unroll
  for (int o = 1; o < 64; o <<= 1) { su += __shfl_xor(su, o); sv += __shfl_xor(sv, o); }
  if (lane == 0) { u[row] = su + b1[row]; v[row] = sv; }
}

// ---------------------------------------------------------------------------
// Fused GEMM: C = tanh(epilogue(A[64 rows, K=512] @ W[,512]^T))
// A staged full-K in LDS once (64KB, swizzled) -> in-place C writes are safe.
// MODE 0: LN-affine epilogue  tanh(rstd_m*G - murs_m*v_n + u_n)   (u has +b1)
// MODE 1: bias epilogue       tanh(G + bias_n)
// grid: M/64 blocks x 256 thr (4 waves: 2n x 2m over [64m x 128n] per n-tile).
// ---------------------------------------------------------------------------
template<int MODE>
__global__ __launch_bounds__(256, 2) void gemm_fused(
    const uint16_t* __restrict__ Abase, const uint16_t* __restrict__ W,
    uint16_t* __restrict__ C, int ntiles,
    const float* __restrict__ rstd_a, const float* __restrict__ murs_a,
    const float* __restrict__ uvec, const float* __restrict__ vvec,
    const float* __restrict__ bias)
{
  __shared__ uint16_t At[64 * 512];   // 65536 B
  const int tid  = threadIdx.x;
  const int lane = tid & 63;
  const int wv   = tid >> 6;
  const size_t mbase = (size_t)blockIdx.x * 64;

  // stage 64 rows x full K, pre-swizzled source -> linear LDS dest
  for (int r8 = 0; r8 < 16; ++r8) {
    int row = wv * 16 + r8;
    int sb  = (lane * 16) ^ ((row & 7) << 4);       // byte pos in 1024B row
    gll16(Abase + (mbase + row) * 512 + sb / 2, At + row * 512);
  }
  __syncthreads();

  const int fr = lane & 15, kg = lane >> 4;
  const int mloc = (wv & 1) * 32;
  const int nhalf = (wv >> 1) * 64;

  for (int nt = 0; nt < ntiles; ++nt) {
    const int nbase = nt * 128 + nhalf;
    f32x4 vz = {0.f, 0.f, 0.f, 0.f};
    f32x4 acc[4][2];
    #pragma unroll
    for (int i = 0; i < 4; ++i) { acc[i][0] = vz; acc[i][1] = vz; }

    #pragma unroll 4
    for (int kb = 0; kb < 16; ++kb) {
      const int ke = kb * 32 + kg * 8;              // element offset in K
      bf16x8 wf[4];
      #pragma unroll
      for (int i = 0; i < 4; ++i)
        wf[i] = *(const bf16x8*)(W + (size_t)(nbase + i * 16 + fr) * 512 + ke);
      bf16x8 af[2];
      #pragma unroll
      for (int j = 0; j < 2; ++j) {
        int mr = mloc + j * 16 + fr;
        af[j] = *(const bf16x8*)((const char*)At + ((mr * 1024 + ke * 2) ^ ((mr & 7) << 4)));
      }
      #pragma unroll
      for (int i = 0; i < 4; ++i)
        #pragma unroll
        for (int j = 0; j < 2; ++j)
          acc[i][j] = __builtin_amdgcn_mfma_f32_16x16x32_bf16(wf[i], af[j], acc[i][j], 0, 0, 0);
    }

    #pragma unroll
    for (int j = 0; j < 2; ++j) {
      size_t m = mbase + mloc + j * 16 + fr;
      float rs = 0.f, mrs = 0.f;
      if constexpr (MODE == 0) { rs = rstd_a[m]; mrs = murs_a[m]; }
      #pragma unroll
      for (int i = 0; i < 4; ++i) {
        int n = nbase + i * 16 + kg * 4;
        float o0, o1, o2, o3;
        if constexpr (MODE == 0) {
          float4 uu = *(const float4*)(uvec + n);
          float4 vv = *(const float4*)(vvec + n);
          o0 = tanh_fast(rs * acc[i][j][0] - mrs * vv.x + uu.x);
          o1 = tanh_fast(rs * acc[i][j][1] - mrs * vv.y + uu.y);
          o2 = tanh_fast(rs * acc[i][j][2] - mrs * vv.z + uu.z);
          o3 = tanh_fast(rs * acc[i][j][3] - mrs * vv.w + uu.w);
        } else {
          float4 bb = *(const float4*)(bias + n);
          o0 = tanh_fast(acc[i][j][0] + bb.x);
          o1 = tanh_fast(acc[i][j][1] + bb.y);
          o2 = tanh_fast(acc[i][j][2] + bb.z);
          o3 = tanh_fast(acc[i][j][3] + bb.w);
        }
        uint32_t lo = (uint32_t)f2bf(o0) | ((uint32_t)f2bf(o1) << 16);
        uint32_t hi = (uint32_t)f2bf(o2) | ((uint32_t)f2bf(o3) << 16);
        *(uint64_t*)(C + m * 512 + n) = (uint64_t)lo | ((uint64_t)hi << 32);
      }
    }
    __syncthreads();  // keep waves together before next n-tile reads At
  }
}

// ---------------------------------------------------------------------------
// value[m] = a2[m,:256] . Wv + bv   (a2 at stride 512; one wave per row)
// ---------------------------------------------------------------------------
__global__ void gemv_kernel(const uint16_t* __restrict__ a2, const float* __restrict__ Wv,
                            const float* __restrict__ bv, float* __restrict__ outv)
{
  const int lane = threadIdx.x & 63;
  const size_t row = (size_t)blockIdx.x * 4 + (threadIdx.x >> 6);
  const uint16_t* p = a2 + row * 512 + lane * 4;
  uint64_t v = *(const uint64_t*)p;
  float4 w = *(const float4*)(Wv + lane * 4);
  float d = bf2f((uint16_t)(v & 0xFFFF)) * w.x
          + bf2f((uint16_t)((v >> 16) & 0xFFFF)) * w.y
          + bf2f((uint16_t)((v >> 32) & 0xFFFF)) * w.z
          + bf2f((uint16_t)((v >> 48) & 0xFFFF)) * w.w;
  #pragma unroll
  for (int o = 1; o < 64; o <<= 1) d += __shfl_xor(d, o);
  if (lane == 0) outv[row] = d + bv[0];
}

// ---------------------------------------------------------------------------
// W1 (fold ln_g into columns) then W2, fp32 -> bf16 contiguous.
// ---------------------------------------------------------------------------
__global__ void wconv_kernel(const float* __restrict__ W1, const float* __restrict__ W2,
                             const float* __restrict__ ln_g, uint16_t* __restrict__ dst)
{
  int idx = blockIdx.x * 256 + threadIdx.x;
  int i4 = idx * 4;
  float4 v;
  if (i4 < 262144) {
    v = *(const float4*)(W1 + i4);
    int c = i4 & 511;
    float4 gv = *(const float4*)(ln_g + c);
    v.x *= gv.x; v.y *= gv.y; v.z *= gv.z; v.w *= gv.w;
  } else {
    v = *(const float4*)(W2 + (i4 - 262144));
  }
  uint32_t lo = (uint32_t)f2bf(v.x) | ((uint32_t)f2bf(v.y) << 16);
  uint32_t hi = (uint32_t)f2bf(v.z) | ((uint32_t)f2bf(v.w) << 16);
  *(uint64_t*)(dst + i4) = (uint64_t)lo | ((uint64_t)hi << 32);
}

extern "C" void kernel_launch(void* const* d_in, const int* in_sizes, int n_in,
                              void* d_out, int out_size, void* d_ws, size_t ws_size,
                              hipStream_t stream)
{
  (void)in_sizes; (void)n_in;
  const float* x    = (const float*)d_in[0];
  const float* done = (const float*)d_in[1];
  const float* h0   = (const float*)d_in[2];
  const float* c0   = (const float*)d_in[3];
  const float* W_ih = (const float*)d_in[4];
  const float* W_hh = (const float*)d_in[5];
  const float* b_ih = (const float*)d_in[6];
  const float* b_hh = (const float*)d_in[7];
  const float* ln_g = (const float*)d_in[8];
  const float* ln_b = (const float*)d_in[9];
  const float* W1   = (const float*)d_in[10];
  const float* b1   = (const float*)d_in[11];
  const float* W2   = (const float*)d_in[12];
  const float* b2   = (const float*)d_in[13];
  const float* Wv   = (const float*)d_in[14];
  const float* bv   = (const float*)d_in[15];
  float* out = (float*)d_out;
  char* ws = (char*)d_ws;

  // ws layout (bytes):
  //   0        flg      16384    (8 groups x 32 WG flags, 128B/group block)
  //   16384    wbf      786432   (bf16 W1g | W2)
  //   802816   u,v      4096     (512 f32 each)
  //   806912   rstd     524288
  //   1331200  murs     524288
  //   2097152  hs       134217728  (bf16 [T*B,512]; later a1 in-place, a2 cols 0..255)
  constexpr size_t NEED = 2097152ULL + 134217728ULL;
  if (ws_size < NEED) {
    hipMemsetAsync(d_out, 0, (size_t)out_size * 4, stream);
    return;
  }
  uint32_t* flg  = (uint32_t*)ws;
  uint16_t* wbf  = (uint16_t*)(ws + 16384);
  float*    uv_u = (float*)(ws + 802816);
  float*    uv_v = (float*)(ws + 802816 + 2048);
  float*    rstd = (float*)(ws + 806912);
  float*    murs = (float*)(ws + 1331200);
  uint16_t* hsb  = (uint16_t*)(ws + 2097152);

  hipMemsetAsync(flg, 0, 16384, stream);
  hipLaunchKernelGGL(wconv_kernel, dim3(384), dim3(256), 0, stream, W1, W2, ln_g, wbf);
  hipLaunchKernelGGL(uv_kernel, dim3(128), dim3(256), 0, stream, W1, ln_g, ln_b, b1, uv_u, uv_v);
  hipFuncSetAttribute((const void*)lstm_kernel,
                      hipFuncAttributeMaxDynamicSharedMemorySize, 131072);
  hipLaunchKernelGGL(lstm_kernel, dim3(256), dim3(256), 119040, stream,
                     x, done, h0, c0, W_ih, W_hh, b_ih, b_hh, hsb, flg, out);
  hipLaunchKernelGGL(ln_stats_kernel, dim3(32768), dim3(256), 0, stream, hsb, rstd, murs);
  // GEMM1: a1 = tanh(LN(h) @ W1^T + b1), in-place over hs
  hipLaunchKernelGGL((gemm_fused<0>), dim3(2048), dim3(256), 0, stream,
                     hsb, wbf, hsb, 4, rstd, murs, uv_u, uv_v, (const float*)nullptr);
  // GEMM2: a2 = tanh(a1 @ W2^T + b2), in-place over hs cols [0,256)
  hipLaunchKernelGGL((gemm_fused<1>), dim3(2048), dim3(256), 0, stream,
                     hsb, wbf + 262144, hsb, 2,
                     (const float*)nullptr, (const float*)nullptr,
                     (const float*)nullptr, (const float*)nullptr, b2);
  hipLaunchKernelGGL(gemv_kernel, dim3(32768), dim3(256), 0, stream, hsb, Wv, bv, out);
}